// Round 5
// baseline (232.150 us; speedup 1.0000x reference)
//
#include <hip/hip_runtime.h>
#include <stdint.h>

// Problem constants (fixed by reference: R=C=256, S=32, B=64)
#define N_NEUR  65536
#define NNZ_E   2162688          // N * 33
#define NBUK    4096             // buckets of 16 destination rows
#define BSH     4                // bucket = row >> 4
#define BROWS   16
#define EPB     8192             // edges per bin block
#define NBLK_E  (NNZ_E / EPB)    // 264 exactly
#define CHUNK   2048             // gather staging chunk (16 KB ebuf)

// Workspace layout (bytes):
//   xt    @ 0         : N*64*4 = 16,777,216   x transposed [N][64]
//   bcnt  @ 16777216  : 4096*4
//   boffs @ 16793600  : 4096*4
//   gcur  @ 16809984  : 4096*4
//   csr   @ 16826368  : NNZ*8  = 17,301,504   packed (val:f32 | row:u16 | col:u16)

// ---------------- K1: fused transpose (blocks 0..1023) + bucket hist (1024..1287) ----
__global__ __launch_bounds__(256) void k_front(const float* __restrict__ x,
                                               float* __restrict__ xt,
                                               const int* __restrict__ rows,
                                               int* __restrict__ bcnt) {
  __shared__ float smem[64 * 65];            // union: transpose tile / hist counters
  const int t = threadIdx.x;
  if (blockIdx.x < 1024) {
    float (*tile)[65] = (float (*)[65])smem;
    const int n0 = blockIdx.x * 64;
    const int lane = t & 63;
    const int w = t >> 6;
    #pragma unroll
    for (int bb = w; bb < 64; bb += 4)
      tile[bb][lane] = x[(size_t)bb * N_NEUR + n0 + lane];
    __syncthreads();
    #pragma unroll
    for (int nn = w; nn < 64; nn += 4)
      xt[(size_t)(n0 + nn) * 64 + lane] = tile[lane][nn];
  } else {
    int* lh = (int*)smem;                    // 4096 counters
    #pragma unroll
    for (int q = 0; q < NBUK / 256; ++q) lh[q * 256 + t] = 0;
    __syncthreads();
    const int e0 = (blockIdx.x - 1024) * EPB;
    #pragma unroll
    for (int k = 0; k < EPB / 256; ++k)
      atomicAdd(&lh[rows[e0 + k * 256 + t] >> BSH], 1);
    __syncthreads();
    #pragma unroll
    for (int q = 0; q < NBUK / 256; ++q) {
      const int v = lh[q * 256 + t];
      if (v) atomicAdd(&bcnt[q * 256 + t], v);
    }
  }
}

// ---------------- K2: exclusive scan over 4096 bucket counts (1 block) ----------------
__device__ inline int wave_incl_scan(int v, int lane) {
  #pragma unroll
  for (int off = 1; off < 64; off <<= 1) {
    int tv = __shfl_up(v, off, 64);
    if (lane >= off) v += tv;
  }
  return v;
}

__global__ __launch_bounds__(256) void k_bscan(const int* __restrict__ bcnt,
                                               int* __restrict__ boffs,
                                               int* __restrict__ gcur) {
  const int t = threadIdx.x, lane = t & 63, w = t >> 6;
  int c[16], s = 0;
  #pragma unroll
  for (int k = 0; k < 16; ++k) { c[k] = bcnt[t * 16 + k]; s += c[k]; }
  int incl = wave_incl_scan(s, lane);
  __shared__ int wsum[4];
  if (lane == 63) wsum[w] = incl;
  __syncthreads();
  int base = 0;
  for (int i = 0; i < w; ++i) base += wsum[i];
  int run = base + incl - s;
  #pragma unroll
  for (int k = 0; k < 16; ++k) {
    boffs[t * 16 + k] = run;
    gcur[t * 16 + k]  = run;
    run += c[k];
  }
}

// ---------------- K3: bucket-bin edges with coalesced chunk writes ----------------
__global__ __launch_bounds__(256) void k_bin(const int* __restrict__ rows,
                                             const float* __restrict__ vals,
                                             int* __restrict__ gcur,
                                             uint64_t* __restrict__ csr) {
  __shared__ int lc[NBUK];        // 16 KB
  __shared__ int lofs[NBUK];      // 16 KB
  __shared__ int sbase[NBUK];     // 16 KB
  __shared__ int wsum[4];
  __shared__ uint64_t ebuf[EPB];  // 64 KB
  const int t = threadIdx.x, lane = t & 63, w = t >> 6;
  #pragma unroll
  for (int q = 0; q < NBUK / 256; ++q) lc[q * 256 + t] = 0;
  __syncthreads();
  const int e0 = blockIdx.x * EPB;
  int rcache[EPB / 256];
  #pragma unroll
  for (int k = 0; k < EPB / 256; ++k) {
    const int r = rows[e0 + k * 256 + t];
    rcache[k] = r;
    atomicAdd(&lc[r >> BSH], 1);
  }
  __syncthreads();
  {
    int c[16], s = 0;
    #pragma unroll
    for (int k = 0; k < 16; ++k) { c[k] = lc[t * 16 + k]; s += c[k]; }
    int incl = wave_incl_scan(s, lane);
    if (lane == 63) wsum[w] = incl;
    __syncthreads();
    int base = 0;
    for (int i = 0; i < w; ++i) base += wsum[i];
    int run = base + incl - s;
    #pragma unroll
    for (int k = 0; k < 16; ++k) { lofs[t * 16 + k] = run; run += c[k]; }
  }
  __syncthreads();
  #pragma unroll
  for (int q = 0; q < NBUK / 256; ++q) {
    const int bb = q * 256 + t;
    const int c = lc[bb];
    if (c) sbase[bb] = atomicAdd(&gcur[bb], c) - lofs[bb];
  }
  __syncthreads();
  #pragma unroll
  for (int k = 0; k < EPB / 256; ++k) {
    const int e = e0 + k * 256 + t;
    const int r = rcache[k];
    const uint32_t c = (uint32_t)e / 33u;      // cols[e] == e / 33 structurally
    const uint64_t pk = ((uint64_t)__float_as_uint(vals[e]) << 32) |
                        ((uint32_t)r << 16) | c;
    const int pos = atomicAdd(&lofs[r >> BSH], 1);
    ebuf[pos] = pk;
  }
  __syncthreads();
  #pragma unroll
  for (int k = 0; k < EPB / 256; ++k) {
    const int idx = k * 256 + t;
    const uint64_t pk = ebuf[idx];
    const int bb = (int)((pk >> (16 + BSH)) & (NBUK - 1));
    csr[sbase[bb] + idx] = pk;
  }
}

// ---------------- K4: per-bucket chunked sort + cooperative gather ----------------
__global__ __launch_bounds__(256) void k_gather(const float* __restrict__ xt,
                                                const int* __restrict__ boffs,
                                                const int* __restrict__ bcnt,
                                                const uint64_t* __restrict__ csr,
                                                float* __restrict__ out) {
  __shared__ uint64_t ebuf[CHUNK];     // 16 KB
  __shared__ float tile[BROWS][65];    // 4.2 KB
  __shared__ int lhist[BROWS], lofs[BROWS], lcur[BROWS];
  const int t = threadIdx.x, lane = t & 63, w = t >> 6;
  const int bid = blockIdx.x;
  const int g = (bid & 7) * (NBUK / 8) + (bid >> 3);   // XCD-chunked swizzle
  const int r0 = g * BROWS;
  const int beg = boffs[g];
  const int cnt = bcnt[g];
  for (int i = t; i < BROWS * 65; i += 256) ((float*)tile)[i] = 0.f;

  float acc[BROWS];
  #pragma unroll
  for (int r = 0; r < BROWS; ++r) acc[r] = 0.f;

  for (int c0 = 0; c0 < cnt; c0 += CHUNK) {
    const int len = (cnt - c0 < CHUNK) ? (cnt - c0) : CHUNK;
    if (t < BROWS) lhist[t] = 0;
    __syncthreads();
    // pass 1: row histogram (coalesced csr read)
    for (int i = t; i < len; i += 256)
      atomicAdd(&lhist[(int)((csr[beg + c0 + i] >> 16) & (BROWS - 1))], 1);
    __syncthreads();
    if (t == 0) {
      int run = 0;
      #pragma unroll
      for (int r = 0; r < BROWS; ++r) { lofs[r] = run; lcur[r] = run; run += lhist[r]; }
    }
    __syncthreads();
    // pass 2: row-sorted scatter into ebuf (csr re-read is L2-hot)
    for (int i = t; i < len; i += 256) {
      const uint64_t e = csr[beg + c0 + i];
      const int pos = atomicAdd(&lcur[(int)((e >> 16) & (BROWS - 1))], 1);
      ebuf[pos] = e;
    }
    __syncthreads();
    // gather: each row's segment split across all 4 waves
    #pragma unroll
    for (int r = 0; r < BROWS; ++r) {
      const int s = lofs[r];
      const int c = lhist[r];
      const int k0 = (c * w) >> 2;
      const int k1 = (c * (w + 1)) >> 2;
      float a0 = 0.f, a1 = 0.f;
      int k = k0;
      for (; k + 8 <= k1; k += 8) {
        const uint64_t e0 = ebuf[s+k+0], e1 = ebuf[s+k+1], e2 = ebuf[s+k+2], e3 = ebuf[s+k+3];
        const uint64_t e4 = ebuf[s+k+4], e5 = ebuf[s+k+5], e6 = ebuf[s+k+6], e7 = ebuf[s+k+7];
        const float p0 = xt[(int)(e0 & 0xFFFF) * 64 + lane];
        const float p1 = xt[(int)(e1 & 0xFFFF) * 64 + lane];
        const float p2 = xt[(int)(e2 & 0xFFFF) * 64 + lane];
        const float p3 = xt[(int)(e3 & 0xFFFF) * 64 + lane];
        const float p4 = xt[(int)(e4 & 0xFFFF) * 64 + lane];
        const float p5 = xt[(int)(e5 & 0xFFFF) * 64 + lane];
        const float p6 = xt[(int)(e6 & 0xFFFF) * 64 + lane];
        const float p7 = xt[(int)(e7 & 0xFFFF) * 64 + lane];
        a0 = fmaf(__uint_as_float((uint32_t)(e0 >> 32)), p0, a0);
        a1 = fmaf(__uint_as_float((uint32_t)(e1 >> 32)), p1, a1);
        a0 = fmaf(__uint_as_float((uint32_t)(e2 >> 32)), p2, a0);
        a1 = fmaf(__uint_as_float((uint32_t)(e3 >> 32)), p3, a1);
        a0 = fmaf(__uint_as_float((uint32_t)(e4 >> 32)), p4, a0);
        a1 = fmaf(__uint_as_float((uint32_t)(e5 >> 32)), p5, a1);
        a0 = fmaf(__uint_as_float((uint32_t)(e6 >> 32)), p6, a0);
        a1 = fmaf(__uint_as_float((uint32_t)(e7 >> 32)), p7, a1);
      }
      for (; k < k1; ++k) {
        const uint64_t e = ebuf[s + k];
        a0 = fmaf(__uint_as_float((uint32_t)(e >> 32)),
                  xt[(int)(e & 0xFFFF) * 64 + lane], a0);
      }
      acc[r] += a0 + a1;
    }
    __syncthreads();   // ebuf reused next chunk
  }

  // reduce 4 waves' partials into tile
  #pragma unroll
  for (int r = 0; r < BROWS; ++r)
    atomicAdd(&tile[r][lane], acc[r]);
  __syncthreads();
  // coalesced write-out: out[b][r0+rl]
  #pragma unroll
  for (int p = 0; p < (BROWS * 64) / 256; ++p) {
    const int idx = p * 256 + t;
    const int bb = idx >> 4;
    const int rl = idx & (BROWS - 1);
    out[(size_t)bb * N_NEUR + r0 + rl] = tile[rl][bb];
  }
}

extern "C" void kernel_launch(void* const* d_in, const int* in_sizes, int n_in,
                              void* d_out, int out_size, void* d_ws, size_t ws_size,
                              hipStream_t stream) {
  const float* x    = (const float*)d_in[0];
  const float* vals = (const float*)d_in[1];
  const int*   rows = (const int*)d_in[2];
  float* out = (float*)d_out;

  char* ws = (char*)d_ws;
  float*    xt    = (float*)   (ws + 0);
  int*      bcnt  = (int*)     (ws + 16777216);
  int*      boffs = (int*)     (ws + 16793600);
  int*      gcur  = (int*)     (ws + 16809984);
  uint64_t* csr   = (uint64_t*)(ws + 16826368);

  hipMemsetAsync(bcnt, 0, NBUK * sizeof(int), stream);
  k_front<<<1024 + NBLK_E, 256, 0, stream>>>(x, xt, rows, bcnt);
  k_bscan<<<1, 256, 0, stream>>>(bcnt, boffs, gcur);
  k_bin<<<NBLK_E, 256, 0, stream>>>(rows, vals, gcur, csr);
  k_gather<<<NBUK, 256, 0, stream>>>(xt, boffs, bcnt, csr, out);
}

// Round 6
// 112.287 us; speedup vs baseline: 2.0675x; 2.0675x over previous
//
#include <hip/hip_runtime.h>
#include <stdint.h>

// Problem constants (fixed by reference: R=C=256, S=32, B=64)
#define N_NEUR  65536
#define NNZ_E   2162688          // N * 33
#define NBUK    4096             // buckets of 16 destination rows
#define BSH     4                // bucket = row >> 4
#define BROWS   16
#define EPB     4096             // edges per bin block (528 blocks exactly)
#define NBLK_E  (NNZ_E / EPB)    // 528
#define CHUNK   2048             // gather staging chunk (16 KB ebuf)

// Workspace layout (bytes):
//   xt    @ 0         : N*64*4 = 16,777,216   x transposed [N][64]
//   bcnt  @ 16777216  : 4096*4
//   boffs @ 16793600  : 4096*4
//   gcur  @ 16809984  : 4096*4
//   csr   @ 16826368  : NNZ*8  = 17,301,504   packed (val:f32 | row:u16 | col:u16)

// ---------------- K1: fused transpose (blocks 0..1023) + bucket hist (rest) ----
__global__ __launch_bounds__(256) void k_front(const float* __restrict__ x,
                                               float* __restrict__ xt,
                                               const int* __restrict__ rows,
                                               int* __restrict__ bcnt) {
  __shared__ float smem[64 * 65];            // union: transpose tile / hist counters
  const int t = threadIdx.x;
  if (blockIdx.x < 1024) {
    float (*tile)[65] = (float (*)[65])smem;
    const int n0 = blockIdx.x * 64;
    const int lane = t & 63;
    const int w = t >> 6;
    #pragma unroll
    for (int bb = w; bb < 64; bb += 4)
      tile[bb][lane] = x[(size_t)bb * N_NEUR + n0 + lane];
    __syncthreads();
    #pragma unroll
    for (int nn = w; nn < 64; nn += 4)
      xt[(size_t)(n0 + nn) * 64 + lane] = tile[lane][nn];
  } else {
    int* lh = (int*)smem;                    // 4096 counters
    #pragma unroll
    for (int q = 0; q < NBUK / 256; ++q) lh[q * 256 + t] = 0;
    __syncthreads();
    const int e0 = (blockIdx.x - 1024) * EPB;
    #pragma unroll
    for (int k = 0; k < EPB / 256; ++k)
      atomicAdd(&lh[rows[e0 + k * 256 + t] >> BSH], 1);
    __syncthreads();
    #pragma unroll
    for (int q = 0; q < NBUK / 256; ++q) {
      const int v = lh[q * 256 + t];
      if (v) atomicAdd(&bcnt[q * 256 + t], v);
    }
  }
}

// ---------------- K2: exclusive scan over 4096 bucket counts (1 block) ----------------
__device__ inline int wave_incl_scan(int v, int lane) {
  #pragma unroll
  for (int off = 1; off < 64; off <<= 1) {
    int tv = __shfl_up(v, off, 64);
    if (lane >= off) v += tv;
  }
  return v;
}

__global__ __launch_bounds__(256) void k_bscan(const int* __restrict__ bcnt,
                                               int* __restrict__ boffs,
                                               int* __restrict__ gcur) {
  const int t = threadIdx.x, lane = t & 63, w = t >> 6;
  int c[16], s = 0;
  #pragma unroll
  for (int k = 0; k < 16; ++k) { c[k] = bcnt[t * 16 + k]; s += c[k]; }
  int incl = wave_incl_scan(s, lane);
  __shared__ int wsum[4];
  if (lane == 63) wsum[w] = incl;
  __syncthreads();
  int base = 0;
  for (int i = 0; i < w; ++i) base += wsum[i];
  int run = base + incl - s;
  #pragma unroll
  for (int k = 0; k < 16; ++k) {
    boffs[t * 16 + k] = run;
    gcur[t * 16 + k]  = run;
    run += c[k];
  }
}

// ---------------- K3: bucket-bin edges with coalesced chunk writes ----------------
// lc doubles as sbase after the reservation phase (saves 16 KB -> 2 blocks/CU)
__global__ __launch_bounds__(256) void k_bin(const int* __restrict__ rows,
                                             const float* __restrict__ vals,
                                             int* __restrict__ gcur,
                                             uint64_t* __restrict__ csr) {
  __shared__ int lc[NBUK];        // 16 KB  (count, then sbase)
  __shared__ int lofs[NBUK];      // 16 KB  (scan, then cursor)
  __shared__ int wsum[4];
  __shared__ uint64_t ebuf[EPB];  // 32 KB
  const int t = threadIdx.x, lane = t & 63, w = t >> 6;
  #pragma unroll
  for (int q = 0; q < NBUK / 256; ++q) lc[q * 256 + t] = 0;
  __syncthreads();
  const int e0 = blockIdx.x * EPB;
  int rcache[EPB / 256];
  #pragma unroll
  for (int k = 0; k < EPB / 256; ++k) {
    const int r = rows[e0 + k * 256 + t];
    rcache[k] = r;
    atomicAdd(&lc[r >> BSH], 1);
  }
  __syncthreads();
  {  // exclusive scan lc[4096] -> lofs (thread-chunked 16)
    int c[16], s = 0;
    #pragma unroll
    for (int k = 0; k < 16; ++k) { c[k] = lc[t * 16 + k]; s += c[k]; }
    int incl = wave_incl_scan(s, lane);
    if (lane == 63) wsum[w] = incl;
    __syncthreads();
    int base = 0;
    for (int i = 0; i < w; ++i) base += wsum[i];
    int run = base + incl - s;
    #pragma unroll
    for (int k = 0; k < 16; ++k) { lofs[t * 16 + k] = run; run += c[k]; }
  }
  __syncthreads();
  // reserve contiguous global chunk per non-empty bucket; lc[bb] := sbase
  #pragma unroll
  for (int q = 0; q < NBUK / 256; ++q) {
    const int bb = q * 256 + t;
    const int c = lc[bb];
    if (c) lc[bb] = atomicAdd(&gcur[bb], c) - lofs[bb];
  }
  __syncthreads();
  // local bucket-sort into ebuf (lofs doubles as cursor)
  #pragma unroll
  for (int k = 0; k < EPB / 256; ++k) {
    const int e = e0 + k * 256 + t;
    const int r = rcache[k];
    const uint32_t c = (uint32_t)e / 33u;      // cols[e] == e / 33 structurally
    const uint64_t pk = ((uint64_t)__float_as_uint(vals[e]) << 32) |
                        ((uint32_t)r << 16) | c;
    const int pos = atomicAdd(&lofs[r >> BSH], 1);
    ebuf[pos] = pk;
  }
  __syncthreads();
  // coalesced write-out: same-bucket runs -> consecutive global targets
  #pragma unroll
  for (int k = 0; k < EPB / 256; ++k) {
    const int idx = k * 256 + t;
    const uint64_t pk = ebuf[idx];
    const int bb = (int)((pk >> (16 + BSH)) & (NBUK - 1));
    csr[lc[bb] + idx] = pk;
  }
}

// ---------------- K4: per-bucket chunked reg-staged sort + wave-owned gather ----------
__global__ __launch_bounds__(256) void k_gather(const float* __restrict__ xt,
                                                const int* __restrict__ boffs,
                                                const int* __restrict__ bcnt,
                                                const uint64_t* __restrict__ csr,
                                                float* __restrict__ out) {
  __shared__ uint64_t ebuf[CHUNK];     // 16 KB
  __shared__ float tile[BROWS][65];    // 4.2 KB
  __shared__ int lhist[BROWS], lofs[BROWS], lcur[BROWS];
  const int t = threadIdx.x, lane = t & 63, w = t >> 6;
  const int bid = blockIdx.x;
  const int g = (bid & 7) * (NBUK / 8) + (bid >> 3);   // XCD-chunked swizzle
  const int r0 = g * BROWS;
  const int beg = boffs[g];
  const int cnt = bcnt[g];

  float acc[4] = {0.f, 0.f, 0.f, 0.f};   // wave w owns rows w*4 .. w*4+3

  for (int c0 = 0; c0 < cnt; c0 += CHUNK) {
    const int len = (cnt - c0 < CHUNK) ? (cnt - c0) : CHUNK;
    if (t < BROWS) lhist[t] = 0;
    __syncthreads();
    // stage to regs + LDS row histogram (single coalesced csr read)
    uint64_t E[CHUNK / 256];
    #pragma unroll
    for (int u = 0; u < CHUNK / 256; ++u) {
      const int i = u * 256 + t;
      if (i < len) {
        const uint64_t e = csr[beg + c0 + i];
        E[u] = e;
        atomicAdd(&lhist[(int)((e >> 16) & (BROWS - 1))], 1);
      }
    }
    __syncthreads();
    if (t == 0) {
      int run = 0;
      #pragma unroll
      for (int r = 0; r < BROWS; ++r) { lofs[r] = run; lcur[r] = run; run += lhist[r]; }
    }
    __syncthreads();
    // scatter into row-sorted LDS order
    #pragma unroll
    for (int u = 0; u < CHUNK / 256; ++u) {
      const int i = u * 256 + t;
      if (i < len) {
        const int rlo = (int)((E[u] >> 16) & (BROWS - 1));
        const int pos = atomicAdd(&lcur[rlo], 1);
        ebuf[pos] = E[u];
      }
    }
    __syncthreads();
    // gather: wave w owns rows w*4..w*4+3; 16-deep MLP, 4 accumulators
    #pragma unroll
    for (int q = 0; q < 4; ++q) {
      const int rlo = w * 4 + q;
      const int s = __builtin_amdgcn_readfirstlane(lofs[rlo]);
      const int c = __builtin_amdgcn_readfirstlane(lhist[rlo]);
      float a0 = 0.f, a1 = 0.f, a2 = 0.f, a3 = 0.f;
      int k = 0;
      for (; k + 16 <= c; k += 16) {
        uint64_t e[16];
        float p[16];
        #pragma unroll
        for (int u = 0; u < 16; ++u) e[u] = ebuf[s + k + u];   // uniform broadcast
        #pragma unroll
        for (int u = 0; u < 16; ++u)
          p[u] = xt[(int)(e[u] & 0xFFFF) * 64 + lane];         // 256B coalesced
        #pragma unroll
        for (int u = 0; u < 16; ++u) {
          const float v = __uint_as_float((uint32_t)(e[u] >> 32));
          if ((u & 3) == 0) a0 = fmaf(v, p[u], a0);
          else if ((u & 3) == 1) a1 = fmaf(v, p[u], a1);
          else if ((u & 3) == 2) a2 = fmaf(v, p[u], a2);
          else a3 = fmaf(v, p[u], a3);
        }
      }
      for (; k + 4 <= c; k += 4) {
        const uint64_t e0 = ebuf[s+k], e1 = ebuf[s+k+1], e2 = ebuf[s+k+2], e3 = ebuf[s+k+3];
        const float p0 = xt[(int)(e0 & 0xFFFF) * 64 + lane];
        const float p1 = xt[(int)(e1 & 0xFFFF) * 64 + lane];
        const float p2 = xt[(int)(e2 & 0xFFFF) * 64 + lane];
        const float p3 = xt[(int)(e3 & 0xFFFF) * 64 + lane];
        a0 = fmaf(__uint_as_float((uint32_t)(e0 >> 32)), p0, a0);
        a1 = fmaf(__uint_as_float((uint32_t)(e1 >> 32)), p1, a1);
        a2 = fmaf(__uint_as_float((uint32_t)(e2 >> 32)), p2, a2);
        a3 = fmaf(__uint_as_float((uint32_t)(e3 >> 32)), p3, a3);
      }
      for (; k < c; ++k) {
        const uint64_t e = ebuf[s + k];
        a0 = fmaf(__uint_as_float((uint32_t)(e >> 32)),
                  xt[(int)(e & 0xFFFF) * 64 + lane], a0);
      }
      acc[q] += (a0 + a1) + (a2 + a3);
    }
    __syncthreads();   // ebuf/lhist reused next chunk
  }

  // each row owned by exactly one wave: direct tile write, no atomics
  #pragma unroll
  for (int q = 0; q < 4; ++q)
    tile[w * 4 + q][lane] = acc[q];
  __syncthreads();
  // coalesced write-out: out[b][r0+rl]
  #pragma unroll
  for (int p = 0; p < (BROWS * 64) / 256; ++p) {
    const int idx = p * 256 + t;
    const int bb = idx >> 4;
    const int rl = idx & (BROWS - 1);
    out[(size_t)bb * N_NEUR + r0 + rl] = tile[rl][bb];
  }
}

extern "C" void kernel_launch(void* const* d_in, const int* in_sizes, int n_in,
                              void* d_out, int out_size, void* d_ws, size_t ws_size,
                              hipStream_t stream) {
  const float* x    = (const float*)d_in[0];
  const float* vals = (const float*)d_in[1];
  const int*   rows = (const int*)d_in[2];
  float* out = (float*)d_out;

  char* ws = (char*)d_ws;
  float*    xt    = (float*)   (ws + 0);
  int*      bcnt  = (int*)     (ws + 16777216);
  int*      boffs = (int*)     (ws + 16793600);
  int*      gcur  = (int*)     (ws + 16809984);
  uint64_t* csr   = (uint64_t*)(ws + 16826368);

  hipMemsetAsync(bcnt, 0, NBUK * sizeof(int), stream);
  k_front<<<1024 + NBLK_E, 256, 0, stream>>>(x, xt, rows, bcnt);
  k_bscan<<<1, 256, 0, stream>>>(bcnt, boffs, gcur);
  k_bin<<<NBLK_E, 256, 0, stream>>>(rows, vals, gcur, csr);
  k_gather<<<NBUK, 256, 0, stream>>>(xt, boffs, bcnt, csr, out);
}